// Round 6
// baseline (47.928 us; speedup 1.0000x reference)
//
#include <hip/hip_runtime.h>
#include <math.h>

// Fused RoPE, single streaming kernel.
// R5: full unroll (16 independent load/store pairs in flight) + 32-bit quad
// indices (offsets < 2^27 elements) to cut 64-bit address VALU latency.
// out[..,s,2k]   = cos_k*x[2k] - sin_k*x[2k+1]
// out[..,s,2k+1] = sin_k*x[2k] + cos_k*x[2k+1],  angle = pos[s] * 10000^(-k/64)
//
// Geometry: x/out are [BH=64][S=4096][D=128] f32 = 8,388,608 float4-quads.
// Grid fixed at 2048x256 = 524,288 threads = 16,384 rows x 32 quads.
// Each thread owns ONE (s, quad) pair: cos/sin computed once in the prologue
// (f32 exp2f+sincosf; angle<=4095 rad -> sin/cos err ~4e-4 vs threshold 0.114).
// Loop walks 16 bh-planes doing pure load -> 4 FMA -> store.
// The rope[4096,128,128] input is never read.

#define S_DIM 4096
#define GRID  2048
#define BLOCK 256
#define ROW_STRIDE_Q 524288   // 16384 rows * 32 quads per sweep (fits in int)

typedef float f32x4 __attribute__((ext_vector_type(4)));

__global__ __launch_bounds__(BLOCK) void rope_fused_kernel(
    const float* __restrict__ x,
    const int*   __restrict__ pos,
    float*       __restrict__ out)
{
    const int t    = blockIdx.x * BLOCK + threadIdx.x;  // [0, 524288)
    const int q    = t & 31;                            // quad within the 128-elem row
    const int row0 = t >> 5;                            // [0, 16384) = bh0*4096 + s
    const int s    = row0 & (S_DIM - 1);

    const float fp = (float)pos[s];
    // inv_freq[k] = 10000^(-k/64); pairs k = 2q, 2q+1. One exp2f, second via ratio.
    const float NLOG  = -0.2076205059304657f;           // -log2(10000)/64
    const float RSTEP =  0.8659643233600653f;           // 10000^(-1/64)
    const float a0 = fp * exp2f(NLOG * (float)(2 * q));
    const float a1 = a0 * RSTEP;
    float s0, c0, s1, c1;
    sincosf(a0, &s0, &c0);
    sincosf(a1, &s1, &c1);

    const f32x4* __restrict__ x4 = (const f32x4*)x;
    f32x4*       __restrict__ o4 = (f32x4*)out;
    const int g0 = row0 * 32 + q;                       // max 8,388,607 — int-safe

    #pragma unroll 16
    for (int i = 0; i < 16; ++i) {
        const int g = g0 + i * ROW_STRIDE_Q;
        const f32x4 xv = x4[g];
        f32x4 ov;
        ov.x = c0 * xv.x - s0 * xv.y;
        ov.y = s0 * xv.x + c0 * xv.y;
        ov.z = c1 * xv.z - s1 * xv.w;
        ov.w = s1 * xv.z + c1 * xv.w;
        o4[g] = ov;
    }
}

extern "C" void kernel_launch(void* const* d_in, const int* in_sizes, int n_in,
                              void* d_out, int out_size, void* d_ws, size_t ws_size,
                              hipStream_t stream) {
    const float* x   = (const float*)d_in[0];
    const int*   pos = (const int*)d_in[1];
    // d_in[2] (rope) intentionally unused — recomputed analytically.
    float* out = (float*)d_out;

    rope_fused_kernel<<<GRID, BLOCK, 0, stream>>>(x, pos, out);
}

// Round 7
// 46.920 us; speedup vs baseline: 1.0215x; 1.0215x over previous
//
#include <hip/hip_runtime.h>
#include <math.h>

// Fused RoPE, single streaming kernel.
// R7: revert to unroll-4 (R5's best: unroll-16 regressed 3%); replace ocml
// sincosf prologue with hardware v_sin/v_cos on fract-reduced revolutions
// (angle err <= ~4e-4 vs threshold 0.114).
//
// out[..,s,2k]   = cos_k*x[2k] - sin_k*x[2k+1]
// out[..,s,2k+1] = sin_k*x[2k] + cos_k*x[2k+1],  angle = pos[s] * 10000^(-k/64)
//
// Geometry: x/out are [BH=64][S=4096][D=128] f32 = 8,388,608 float4-quads.
// Grid fixed at 2048x256 = 524,288 threads = 16,384 rows x 32 quads.
// Each thread owns ONE (s, quad) pair; loop walks 16 bh-planes doing pure
// load -> 4 FMA -> store. The rope[4096,128,128] input is never read.

#define S_DIM 4096
#define GRID  2048
#define BLOCK 256
#define ROW_STRIDE_Q 524288   // 16384 rows * 32 quads per sweep (int-safe)

typedef float f32x4 __attribute__((ext_vector_type(4)));

__device__ __forceinline__ void fast_sincos(float ang, float* s, float* c) {
    // hardware trig: input in revolutions, fract-reduced
    const float INV2PI = 0.15915493667125702f;
    float rev = ang * INV2PI;
    rev = rev - floorf(rev);
    *s = __builtin_amdgcn_sinf(rev);
    *c = __builtin_amdgcn_cosf(rev);
}

__global__ __launch_bounds__(BLOCK) void rope_fused_kernel(
    const float* __restrict__ x,
    const int*   __restrict__ pos,
    float*       __restrict__ out)
{
    const int t    = blockIdx.x * BLOCK + threadIdx.x;  // [0, 524288)
    const int q    = t & 31;                            // quad within the 128-elem row
    const int row0 = t >> 5;                            // [0, 16384) = bh0*4096 + s
    const int s    = row0 & (S_DIM - 1);

    const float fp = (float)pos[s];
    // inv_freq[k] = 10000^(-k/64); pairs k = 2q, 2q+1. One exp2f, second via ratio.
    const float NLOG  = -0.2076205059304657f;           // -log2(10000)/64
    const float RSTEP =  0.8659643233600653f;           // 10000^(-1/64)
    const float a0 = fp * exp2f(NLOG * (float)(2 * q));
    const float a1 = a0 * RSTEP;
    float s0, c0, s1, c1;
    fast_sincos(a0, &s0, &c0);
    fast_sincos(a1, &s1, &c1);

    const f32x4* __restrict__ x4 = (const f32x4*)x;
    f32x4*       __restrict__ o4 = (f32x4*)out;
    const int g0 = row0 * 32 + q;                       // max 8,388,607 — int-safe

    #pragma unroll 4
    for (int i = 0; i < 16; ++i) {
        const int g = g0 + i * ROW_STRIDE_Q;
        const f32x4 xv = x4[g];
        f32x4 ov;
        ov.x = c0 * xv.x - s0 * xv.y;
        ov.y = s0 * xv.x + c0 * xv.y;
        ov.z = c1 * xv.z - s1 * xv.w;
        ov.w = s1 * xv.z + c1 * xv.w;
        o4[g] = ov;
    }
}

extern "C" void kernel_launch(void* const* d_in, const int* in_sizes, int n_in,
                              void* d_out, int out_size, void* d_ws, size_t ws_size,
                              hipStream_t stream) {
    const float* x   = (const float*)d_in[0];
    const int*   pos = (const int*)d_in[1];
    // d_in[2] (rope) intentionally unused — recomputed analytically.
    float* out = (float*)d_out;

    rope_fused_kernel<<<GRID, BLOCK, 0, stream>>>(x, pos, out);
}